// Round 8
// baseline (3268.270 us; speedup 1.0000x reference)
//
#include <hip/hip_runtime.h>
#include <math.h>

#define TT 512
#define BB 256
#define OBS 128
#define ACT 32
#define HID 512
#define AUX_SC 0x11  // SC0|SC1 cache policy: device-scope coherent (bypass L1/L2, read LLC)

typedef unsigned short u16;
typedef unsigned int u32;
typedef __attribute__((ext_vector_type(8))) short bf16x8;  // 8 bf16 = 4 VGPRs
typedef __attribute__((ext_vector_type(4))) float f32x4;

__device__ __forceinline__ u16 f2bf(float v) {
  u32 u = __float_as_uint(v);
  u = (u + 0x7fff + ((u >> 16) & 1)) >> 16;  // RNE
  return (u16)u;
}

// fast transcendentals (v_exp_f32-based) — bf16-accurate, saturate-safe
__device__ __forceinline__ float fast_sigmoid(float x) {
  return 1.f / (1.f + __expf(-x));
}
__device__ __forceinline__ float fast_tanh(float x) {
  float e = __expf(-2.f * fabsf(x));   // e in (0,1], no overflow
  float t = (1.f - e) / (1.f + e);
  return copysignf(t, x);
}

// ---------------- init / setup kernels ----------------

__global__ void k_init(double* acc, int* bars, u32* zb) {
  int tid = threadIdx.x;
  if (tid == 0) acc[0] = 0.0;
  for (int i = tid; i < 1024; i += 256) bars[i * 16] = 0;  // per-block flags, 64 B apart
  zb[tid] = 0;                        // 256 u32 = 1 KB zero buffer
}

// dst bf16 [Mp][Kp] = zero-padded convert of src fp32 [M][K]   (head weights)
__global__ void k_convert_pad(const float* __restrict__ src, u16* __restrict__ dst,
                              int M, int K, int Mp, int Kp) {
  const int n = Mp * Kp;
  for (int idx = blockIdx.x * blockDim.x + threadIdx.x; idx < n;
       idx += gridDim.x * blockDim.x) {
    int m = idx / Kp, k = idx - m * Kp;
    float v = (m < M && k < K) ? src[(size_t)m * K + k] : 0.f;
    dst[idx] = f2bf(v);
  }
}

// Build recurrence weight arrays:
// Wr/Wz [512][704]: [whh_gate | wih_gate | 0pad32]; Wnh [512][512]; Wni [512][192];
// bias4 [4][512]: r: bih+bhh, z: bih+bhh, n_i: bih, n_h: bhh
__global__ void k_prep_w(const float* __restrict__ w_ih, const float* __restrict__ w_hh,
                         const float* __restrict__ b_ih, const float* __restrict__ b_hh,
                         u16* __restrict__ Wr, u16* __restrict__ Wz,
                         u16* __restrict__ Wnh, u16* __restrict__ Wni,
                         float* __restrict__ bias4) {
  const int stride = gridDim.x * blockDim.x;
  const int t0 = blockIdx.x * blockDim.x + threadIdx.x;
  for (int idx = t0; idx < 512 * 704; idx += stride) {
    int j = idx / 704, k = idx - j * 704;
    float vr, vz;
    if (k < 512)      { vr = w_hh[(size_t)j * 512 + k];        vz = w_hh[(size_t)(512 + j) * 512 + k]; }
    else if (k < 672) { vr = w_ih[(size_t)j * 160 + (k - 512)]; vz = w_ih[(size_t)(512 + j) * 160 + (k - 512)]; }
    else              { vr = 0.f; vz = 0.f; }
    Wr[idx] = f2bf(vr); Wz[idx] = f2bf(vz);
  }
  for (int idx = t0; idx < 512 * 512; idx += stride) {
    int j = idx >> 9, k = idx & 511;
    Wnh[idx] = f2bf(w_hh[(size_t)(1024 + j) * 512 + k]);
  }
  for (int idx = t0; idx < 512 * 192; idx += stride) {
    int j = idx / 192, k = idx - j * 192;
    Wni[idx] = f2bf(k < 160 ? w_ih[(size_t)(1024 + j) * 160 + k] : 0.f);
  }
  for (int idx = t0; idx < 2048; idx += stride) {
    int g = idx >> 9, j = idx & 511;
    float v = (g == 0) ? b_ih[j] + b_hh[j]
            : (g == 1) ? b_ih[512 + j] + b_hh[512 + j]
            : (g == 2) ? b_ih[1024 + j] : b_hh[1024 + j];
    bias4[idx] = v;
  }
}

// Xb [T*B][160] bf16: row (t,b) = t==0 ? [obs[0],0] : [obs[t-1], action[t-1]]
__global__ void k_pack_x(const float* __restrict__ obs, const float* __restrict__ action,
                         u16* __restrict__ Xb) {
  const int n = TT * BB * 160;
  for (int idx = blockIdx.x * blockDim.x + threadIdx.x; idx < n;
       idx += gridDim.x * blockDim.x) {
    int rr = idx / 160, cc = idx - rr * 160;
    int t = rr / BB, b = rr - t * BB;
    float v;
    if (t == 0) v = (cc < OBS) ? obs[(size_t)b * OBS + cc] : 0.f;
    else        v = (cc < OBS) ? obs[((size_t)(t - 1) * BB + b) * OBS + cc]
                               : action[((size_t)(t - 1) * BB + b) * ACT + (cc - OBS)];
    Xb[idx] = f2bf(v);
  }
}

// ---------------- persistent GRU recurrence (v4: reg-weights, 4 blocks/CU) ----------------
// Grid (32 jt, 32 bt) = 1024 blocks, 4/CU (LDS 22.5 KB). Each block: 8 batch rows x
// 16 j-cols. Gate weights live in REGISTERS (wave w holds its gate's 16jx512k tile as
// 16 bf16x8 frags/lane, loaded once from global): w0=r_h, w1=z_h, w2=n_h, w3=all 3
// x-gates (15 frags). MFMA A-frag rows 8-15 are garbage feeding unused C rows.
// Cross-wave gate exchange via small LDS region. h crosses blocks via LLC only:
// A-h staging uses SC0|SC1 global_load_lds; h stores are relaxed agent atomics
// (write-through). Group barrier (32 jt-blocks sharing bt): per-block flag (64B pad)
// + parallel 32-lane poll; __syncthreads() drains vmcnt so h is LLC-acked before the
// flag store. Flags monotone across chunk launches.
// LDS (u16 units): A-h@0 (16 rows x 512 alloc'd, 8 staged) ; exch@8192 = 6x256 f32.
// Total 11264 u16 = 22528 B.
__global__ __launch_bounds__(256, 4) void k_gru_seq(
    const u16* __restrict__ Wr, const u16* __restrict__ Wz,
    const u16* __restrict__ Wnh, const u16* __restrict__ Wni,
    const float* __restrict__ bias4, const u16* __restrict__ Xb,
    u16* __restrict__ hs,          // [TC][BB][512] bf16 (slot TC-1 carries across launches)
    float* __restrict__ h32c,      // [BB][512] fp32 carry
    const u16* __restrict__ zb,    // 1 KB zeros
    int* __restrict__ bars,        // 1024 flags, stride 16 ints (64 B)
    int t0, int TC)
{
  __shared__ __align__(16) u16 SB[11264];   // 22528 B
  const int jt = blockIdx.x, bt = blockIdx.y;
  const int tid = threadIdx.x, w = tid >> 6, lane = tid & 63;
  const int m16 = lane & 15, q = lane >> 4;

  // ---- load this wave's gate-weight fragments into registers (once) ----
  // frag wf[ks] = W[jt*16+m16][(cb)*8 ..] with cb = ks*4+q  (h-gates: ks 0..15)
  // wave3: wf[ks*3+g] over ks 0..4, g in {ni, r_x, z_x}
  bf16x8 wf[16];
#pragma unroll
  for (int i = 0; i < 16; ++i) wf[i] = (bf16x8){0, 0, 0, 0, 0, 0, 0, 0};
  {
    const int jr = jt * 16 + m16;
    if (w < 3) {
      const u16* Wg = (w == 0) ? Wr : (w == 1) ? Wz : Wnh;
      const int ws_ = (w == 2) ? 512 : 704;
#pragma unroll
      for (int ks = 0; ks < 16; ++ks)
        wf[ks] = *(const bf16x8*)&Wg[(size_t)jr * ws_ + (ks * 4 + q) * 8];
    } else {
#pragma unroll
      for (int ks = 0; ks < 5; ++ks) {
        int cb = ks * 4 + q;
        wf[ks * 3 + 0] = *(const bf16x8*)&Wni[(size_t)jr * 192 + cb * 8];
        wf[ks * 3 + 1] = *(const bf16x8*)&Wr[(size_t)jr * 704 + 512 + cb * 8];
        wf[ks * 3 + 2] = *(const bf16x8*)&Wz[(size_t)jr * 704 + 512 + cb * 8];
      }
    }
  }

  // ---- per-lane A-h stage descriptors: instr (w,n) stages row i = w*2+n (8 rows) ----
  u32 aoff[2];
#pragma unroll
  for (int n = 0; n < 2; ++n) {
    int i = w * 2 + n;
    aoff[n] = (u32)(bt * 8 + i) * 512 + (u32)(lane ^ (i & 7)) * 8;
  }

  // x-row for wave3 A-frag (rows 8-15 garbage; clamp to stay in-bounds)
  int xr = bt * 8 + m16;
  if (xr > 255) xr = 255;

  // ---- per-thread output ownership: tid<128 owns (eb=tid>>4 of 8 rows, ej=tid&15) ----
  const int eb = tid >> 4;
  const int ej = tid & 15;
  const int gj = jt * 16 + ej;
  const int gbrow = bt * 8 + eb;
  const bool own = (tid < 128);
  float br = 0.f, bz = 0.f, bi = 0.f, bh = 0.f, hv = 0.f;
  if (own) {
    br = bias4[gj]; bz = bias4[512 + gj]; bi = bias4[1024 + gj]; bh = bias4[1536 + gj];
    if (t0 > 0) hv = h32c[(size_t)gbrow * 512 + gj];
  }

  u16* As = SB;
  float* exch = (float*)(SB + 8192);
  const int myflag = (bt * 32 + jt) * 16;
  const int pollflag = (bt * 32 + (lane & 31)) * 16;

  for (int s = 0; s < TC; ++s) {
    const int t = t0 + s;
    const int sp = (s == 0) ? TC - 1 : s - 1;
    const u16* hsrc = hs + (size_t)sp * BB * 512;
    const u16* xsrc = Xb + (size_t)t * BB * 160;
    const bool hzero = (t == 0);

    // stage A-h (8 rows, 8 instrs), device-coherent from LLC
#pragma unroll
    for (int n = 0; n < 2; ++n) {
      const u16* g = hzero ? zb : hsrc + aoff[n];
      __builtin_amdgcn_global_load_lds((const __attribute__((address_space(1))) u32*)g,
          (__attribute__((address_space(3))) u32*)(As + (w * 2 + n) * 512), 16, 0, AUX_SC);
    }
    __syncthreads();   // drains vmcnt before ds_read

    f32x4 acc0 = (f32x4){0.f, 0.f, 0.f, 0.f};
    f32x4 acc1 = (f32x4){0.f, 0.f, 0.f, 0.f};
    f32x4 acc2 = (f32x4){0.f, 0.f, 0.f, 0.f};
    if (w < 3) {
#pragma unroll
      for (int ks = 0; ks < 16; ++ks) {
        int cb = ks * 4 + q;
        bf16x8 af = *(const bf16x8*)&As[m16 * 512 + (cb ^ (m16 & 7)) * 8];
        acc0 = __builtin_amdgcn_mfma_f32_16x16x32_bf16(af, wf[ks], acc0, 0, 0, 0);
      }
    } else {
#pragma unroll
      for (int ks = 0; ks < 5; ++ks) {
        int cb = ks * 4 + q;
        bf16x8 af = *(const bf16x8*)&xsrc[(size_t)xr * 160 + cb * 8];
        acc0 = __builtin_amdgcn_mfma_f32_16x16x32_bf16(af, wf[ks * 3 + 0], acc0, 0, 0, 0);  // ni
        acc1 = __builtin_amdgcn_mfma_f32_16x16x32_bf16(af, wf[ks * 3 + 1], acc1, 0, 0, 0);  // r_x
        acc2 = __builtin_amdgcn_mfma_f32_16x16x32_bf16(af, wf[ks * 3 + 2], acc2, 0, 0, 0);  // z_x
      }
    }

    // gate tiles: 0=r_h 1=z_h 2=nh @ w*256 ; 3=ni@768 4=r_x@1024 5=z_x@1280
    // exch index = [C-row = batch row][C-col = j]
    if (w < 3) {
#pragma unroll
      for (int p = 0; p < 4; ++p)
        exch[w * 256 + (q * 4 + p) * 16 + m16] = acc0[p];
    } else {
#pragma unroll
      for (int p = 0; p < 4; ++p) {
        int o = (q * 4 + p) * 16 + m16;
        exch[768 + o]  = acc0[p];
        exch[1024 + o] = acc1[p];
        exch[1280 + o] = acc2[p];
      }
    }
    __syncthreads();   // exch visible; also fences As reads before next-step stage

    // combine + gates (tid<128): exch row m = eb (0..7 real), col = ej
    if (own) {
      float rs  = exch[tid]        + exch[1024 + tid];
      float zs  = exch[256 + tid]  + exch[1280 + tid];
      float nhv = exch[512 + tid];
      float niv = exch[768 + tid];
      float r = fast_sigmoid(rs + br);
      float z = fast_sigmoid(zs + bz);
      float n = fast_tanh(niv + bi + r * (nhv + bh));
      float h = (1.f - z) * n + z * hv;
      hv = h;
      float ho = __shfl_xor(h, 1);
      if ((ej & 1) == 0) {
        u32 pk = (u32)f2bf(h) | ((u32)f2bf(ho) << 16);
        __hip_atomic_store((u32*)&hs[((size_t)s * BB + gbrow) * 512 + gj], pk,
                           __ATOMIC_RELAXED, __HIP_MEMORY_SCOPE_AGENT);
      }
    }

    // flag barrier (32 jt-blocks sharing bt): sync drains vmcnt (h acked at LLC),
    // then one flag store + parallel 32-lane poll.
    __syncthreads();
    if (tid == 0)
      __hip_atomic_store(&bars[myflag], t + 1, __ATOMIC_RELAXED, __HIP_MEMORY_SCOPE_AGENT);
    if (w == 0) {
      int v = __hip_atomic_load(&bars[pollflag], __ATOMIC_RELAXED, __HIP_MEMORY_SCOPE_AGENT);
      while (__any(v < t + 1)) {
        __builtin_amdgcn_s_sleep(1);
        v = __hip_atomic_load(&bars[pollflag], __ATOMIC_RELAXED, __HIP_MEMORY_SCOPE_AGENT);
      }
    }
    __syncthreads();
  }

  if (own) h32c[(size_t)gbrow * 512 + gj] = hv;
}

// ---------------- MFMA GEMM (heads) ----------------
// C[N][M] = act( A[N][K] @ B[Mp][K]^T + bias[M] ); K mult of 64, N mult of 128.
__global__ __launch_bounds__(256) void k_mfma_gemm(
    const u16* __restrict__ A, const u16* __restrict__ B,
    const float* __restrict__ bias,
    float* __restrict__ outf, u16* __restrict__ outb,
    int N, int K, int M, int act)
{
  __shared__ u16 As[128 * 64];
  __shared__ u16 Bs[128 * 64];
  const int bn = blockIdx.y * 128;
  const int bm = blockIdx.x * 128;
  const int tid = threadIdx.x;
  const int w = tid >> 6, lane = tid & 63;
  const int wr = w >> 1, wc = w & 1;

  f32x4 acc[4][4];
#pragma unroll
  for (int i = 0; i < 4; ++i)
#pragma unroll
    for (int j = 0; j < 4; ++j) acc[i][j] = (f32x4){0.f, 0.f, 0.f, 0.f};

  const int lr8 = lane >> 3;
  const int lc8 = lane & 7;

  for (int kt = 0; kt < K; kt += 64) {
    __syncthreads();
#pragma unroll
    for (int i = 0; i < 4; ++i) {
      int r0 = (w * 4 + i) * 8;
      int r = r0 + lr8;
      int c = lc8 ^ (r & 7);
      const u16* ga = A + (size_t)(bn + r) * K + kt + c * 8;
      const u16* gb = B + (size_t)(bm + r) * K + kt + c * 8;
      __builtin_amdgcn_global_load_lds((const __attribute__((address_space(1))) u32*)ga,
                                       (__attribute__((address_space(3))) u32*)(As + r0 * 64), 16, 0, 0);
      __builtin_amdgcn_global_load_lds((const __attribute__((address_space(1))) u32*)gb,
                                       (__attribute__((address_space(3))) u32*)(Bs + r0 * 64), 16, 0, 0);
    }
    __syncthreads();

    const int m16 = lane & 15, q = lane >> 4;
#pragma unroll
    for (int kk = 0; kk < 2; ++kk) {
      bf16x8 af[4], bfr[4];
#pragma unroll
      for (int i = 0; i < 4; ++i) {
        int ra = wr * 64 + i * 16 + m16;
        af[i] = *(const bf16x8*)&As[ra * 64 + ((kk * 4 + q) ^ (ra & 7)) * 8];
        int rb = wc * 64 + i * 16 + m16;
        bfr[i] = *(const bf16x8*)&Bs[rb * 64 + ((kk * 4 + q) ^ (rb & 7)) * 8];
      }
#pragma unroll
      for (int i = 0; i < 4; ++i)
#pragma unroll
        for (int j = 0; j < 4; ++j)
          acc[i][j] = __builtin_amdgcn_mfma_f32_16x16x32_bf16(af[i], bfr[j], acc[i][j], 0, 0, 0);
    }
  }

  const int m16 = lane & 15, q = lane >> 4;
#pragma unroll
  for (int i = 0; i < 4; ++i) {
#pragma unroll
    for (int j = 0; j < 4; ++j) {
      int col = bm + wc * 64 + j * 16 + m16;
      if (col >= M) continue;
      float bs = bias[col];
#pragma unroll
      for (int p = 0; p < 4; ++p) {
        int row = bn + wr * 64 + i * 16 + q * 4 + p;
        float v = acc[i][j][p] + bs;
        if (act) v = (v > 0.f) ? v : (__expf(v) - 1.f);  // fast ELU (bf16-accurate)
        if (outf) outf[(size_t)row * M + col] = v;
        else      outb[(size_t)row * M + col] = f2bf(v);
      }
    }
  }
}

// ---------------- loss ----------------
__global__ __launch_bounds__(256) void k_loss(
    const float* __restrict__ obs, const float* __restrict__ action,
    const float* __restrict__ p_obs, const float* __restrict__ p_act,
    const float* __restrict__ p_rew, double* __restrict__ acc)
{
  const long long n1 = (long long)TT * BB * OBS;
  const long long n2 = (long long)TT * BB * ACT;
  const long long n  = n1 + n2 + n2;
  const float C = 0.91893853320467274178f;  // 0.5*ln(2*pi)
  double s = 0.0;
  for (long long idx = (long long)blockIdx.x * blockDim.x + threadIdx.x; idx < n;
       idx += (long long)gridDim.x * blockDim.x) {
    float d;
    if (idx < n1) {
      d = obs[idx] - p_obs[idx];
    } else if (idx < n1 + n2) {
      long long i = idx - n1;
      d = action[i] - p_act[i];
    } else {
      long long i = idx - n1 - n2;
      d = action[i] - p_rew[i >> 5];
    }
    s += (double)(0.5f * d * d + C);
  }
  __shared__ double red[256];
  red[threadIdx.x] = s;
  __syncthreads();
  for (int off = 128; off > 0; off >>= 1) {
    if ((int)threadIdx.x < off) red[threadIdx.x] += red[threadIdx.x + off];
    __syncthreads();
  }
  if (threadIdx.x == 0) atomicAdd(acc, red[0]);
}

__global__ void k_finalize(const double* __restrict__ acc, float* __restrict__ out) {
  if (threadIdx.x == 0) out[0] = (float)(acc[0] / (double)(TT * BB));
}

// ---------------- launch ----------------

extern "C" void kernel_launch(void* const* d_in, const int* in_sizes, int n_in,
                              void* d_out, int out_size, void* d_ws, size_t ws_size,
                              hipStream_t stream) {
  const float* obs    = (const float*)d_in[0];
  const float* action = (const float*)d_in[1];
  const float* w_ih = (const float*)d_in[3];
  const float* w_hh = (const float*)d_in[4];
  const float* b_ih = (const float*)d_in[5];
  const float* b_hh = (const float*)d_in[6];
  const float* hw[9] = {(const float*)d_in[7],  (const float*)d_in[9],  (const float*)d_in[11],
                        (const float*)d_in[13], (const float*)d_in[15], (const float*)d_in[17],
                        (const float*)d_in[19], (const float*)d_in[21], (const float*)d_in[23]};
  const float* hb[9] = {(const float*)d_in[8],  (const float*)d_in[10], (const float*)d_in[12],
                        (const float*)d_in[14], (const float*)d_in[16], (const float*)d_in[18],
                        (const float*)d_in[20], (const float*)d_in[22], (const float*)d_in[24]};
  const int hM[9]  = {512, 512, 128, 512, 512, 32, 512, 512, 1};
  const int hMp[9] = {512, 512, 128, 512, 512, 128, 512, 512, 128};

  float* out     = (float*)d_out;
  float* pre_obs = out + 1;
  float* pre_act = pre_obs + (size_t)TT * BB * OBS;
  float* pre_rew = pre_act + (size_t)TT * BB * ACT;

  // ---- workspace ----
  char* ws = (char*)d_ws;
  size_t off = 0;
  auto alloc = [&](size_t bytes) { void* p = ws + off; off = (off + bytes + 255) & ~(size_t)255; return p; };
  double* acc  = (double*)alloc(256);
  int* bars    = (int*)alloc(1024 * 64);          // 1024 padded flags
  u32* zerobuf = (u32*)alloc(1024);
  u16* Wr  = (u16*)alloc((size_t)512 * 704 * 2);
  u16* Wz  = (u16*)alloc((size_t)512 * 704 * 2);
  u16* Wnh = (u16*)alloc((size_t)512 * 512 * 2);
  u16* Wni = (u16*)alloc((size_t)512 * 192 * 2);
  float* bias4 = (float*)alloc(2048 * 4);
  u16* headb[9];
  for (int i = 0; i < 9; ++i) headb[i] = (u16*)alloc((size_t)hMp[i] * 512 * 2);
  float* h32c = (float*)alloc((size_t)BB * 512 * 4);
  u16* Xb     = (u16*)alloc((size_t)TT * BB * 160 * 2);   // 41.9 MB
  const size_t fixed = off;

  int TC = 512;
  while (TC > 8 && fixed + 3ull * TC * BB * 512 * 2ull + (1u << 20) > ws_size) TC >>= 1;
  u16* hs_chunk = (u16*)alloc((size_t)TC * BB * 512 * 2);
  u16* tmp1b    = (u16*)alloc((size_t)TC * BB * 512 * 2);
  u16* tmp2b    = (u16*)alloc((size_t)TC * BB * 512 * 2);
  const int CH = TC * BB;
  const int NCH = TT / TC;

  // ---- setup ----
  k_init<<<1, 256, 0, stream>>>(acc, bars, zerobuf);
  k_prep_w<<<512, 256, 0, stream>>>(w_ih, w_hh, b_ih, b_hh, Wr, Wz, Wnh, Wni, bias4);
  for (int i = 0; i < 9; ++i)
    k_convert_pad<<<512, 256, 0, stream>>>(hw[i], headb[i], hM[i], 512, hMp[i], 512);
  k_pack_x<<<4096, 256, 0, stream>>>(obs, action, Xb);

  for (int c = 0; c < NCH; ++c) {
    k_gru_seq<<<dim3(32, 32), 256, 0, stream>>>(
        Wr, Wz, Wnh, Wni, bias4, Xb, hs_chunk, h32c, (const u16*)zerobuf, bars, c * TC, TC);
    for (int h = 0; h < 3; ++h) {
      int M2 = hM[h * 3 + 2], Mp2 = hMp[h * 3 + 2];
      float* outp = (h == 0) ? pre_obs + (size_t)c * CH * OBS
                  : (h == 1) ? pre_act + (size_t)c * CH * ACT
                             : pre_rew + (size_t)c * CH;
      k_mfma_gemm<<<dim3(4, CH / 128), 256, 0, stream>>>(
          hs_chunk, headb[h * 3 + 0], hb[h * 3 + 0], nullptr, tmp1b, CH, 512, 512, 1);
      k_mfma_gemm<<<dim3(4, CH / 128), 256, 0, stream>>>(
          tmp1b, headb[h * 3 + 1], hb[h * 3 + 1], nullptr, tmp2b, CH, 512, 512, 1);
      k_mfma_gemm<<<dim3(Mp2 / 128, CH / 128), 256, 0, stream>>>(
          tmp2b, headb[h * 3 + 2], hb[h * 3 + 2], outp, nullptr, CH, 512, M2, 0);
    }
  }

  k_loss<<<2048, 256, 0, stream>>>(obs, action, pre_obs, pre_act, pre_rew, acc);
  k_finalize<<<1, 64, 0, stream>>>(acc, out);
}

// Round 9
// 2934.132 us; speedup vs baseline: 1.1139x; 1.1139x over previous
//
#include <hip/hip_runtime.h>
#include <math.h>

#define TT 512
#define BB 256
#define OBS 128
#define ACT 32
#define HID 512
#define AUX_SC 0x11  // SC0|SC1 cache policy: device-scope coherent (bypass L1/L2, read LLC)

typedef unsigned short u16;
typedef unsigned int u32;
typedef __attribute__((ext_vector_type(8))) short bf16x8;  // 8 bf16 = 4 VGPRs
typedef __attribute__((ext_vector_type(4))) float f32x4;

__device__ __forceinline__ u16 f2bf(float v) {
  u32 u = __float_as_uint(v);
  u = (u + 0x7fff + ((u >> 16) & 1)) >> 16;  // RNE
  return (u16)u;
}

// fast transcendentals (v_exp_f32-based) — bf16-accurate, saturate-safe
__device__ __forceinline__ float fast_sigmoid(float x) {
  return 1.f / (1.f + __expf(-x));
}
__device__ __forceinline__ float fast_tanh(float x) {
  float e = __expf(-2.f * fabsf(x));   // e in (0,1], no overflow
  float t = (1.f - e) / (1.f + e);
  return copysignf(t, x);
}

// ---------------- init / setup kernels ----------------

__global__ void k_init(double* acc, int* bars, u32* zb) {
  int tid = threadIdx.x;
  if (tid == 0) acc[0] = 0.0;
  for (int i = tid; i < 1024; i += 256) bars[i * 16] = 0;  // per-block flags, 64 B apart
  zb[tid] = 0;                        // 256 u32 = 1 KB zero buffer
}

// dst bf16 [Mp][Kp] = zero-padded convert of src fp32 [M][K]   (head weights)
__global__ void k_convert_pad(const float* __restrict__ src, u16* __restrict__ dst,
                              int M, int K, int Mp, int Kp) {
  const int n = Mp * Kp;
  for (int idx = blockIdx.x * blockDim.x + threadIdx.x; idx < n;
       idx += gridDim.x * blockDim.x) {
    int m = idx / Kp, k = idx - m * Kp;
    float v = (m < M && k < K) ? src[(size_t)m * K + k] : 0.f;
    dst[idx] = f2bf(v);
  }
}

// Build recurrence weight arrays:
// Wr/Wz [512][704]: [whh_gate | wih_gate | 0pad32]; Wnh [512][512]; Wni [512][192];
// bias4 [4][512]: r: bih+bhh, z: bih+bhh, n_i: bih, n_h: bhh
__global__ void k_prep_w(const float* __restrict__ w_ih, const float* __restrict__ w_hh,
                         const float* __restrict__ b_ih, const float* __restrict__ b_hh,
                         u16* __restrict__ Wr, u16* __restrict__ Wz,
                         u16* __restrict__ Wnh, u16* __restrict__ Wni,
                         float* __restrict__ bias4) {
  const int stride = gridDim.x * blockDim.x;
  const int t0 = blockIdx.x * blockDim.x + threadIdx.x;
  for (int idx = t0; idx < 512 * 704; idx += stride) {
    int j = idx / 704, k = idx - j * 704;
    float vr, vz;
    if (k < 512)      { vr = w_hh[(size_t)j * 512 + k];        vz = w_hh[(size_t)(512 + j) * 512 + k]; }
    else if (k < 672) { vr = w_ih[(size_t)j * 160 + (k - 512)]; vz = w_ih[(size_t)(512 + j) * 160 + (k - 512)]; }
    else              { vr = 0.f; vz = 0.f; }
    Wr[idx] = f2bf(vr); Wz[idx] = f2bf(vz);
  }
  for (int idx = t0; idx < 512 * 512; idx += stride) {
    int j = idx >> 9, k = idx & 511;
    Wnh[idx] = f2bf(w_hh[(size_t)(1024 + j) * 512 + k]);
  }
  for (int idx = t0; idx < 512 * 192; idx += stride) {
    int j = idx / 192, k = idx - j * 192;
    Wni[idx] = f2bf(k < 160 ? w_ih[(size_t)(1024 + j) * 160 + k] : 0.f);
  }
  for (int idx = t0; idx < 2048; idx += stride) {
    int g = idx >> 9, j = idx & 511;
    float v = (g == 0) ? b_ih[j] + b_hh[j]
            : (g == 1) ? b_ih[512 + j] + b_hh[512 + j]
            : (g == 2) ? b_ih[1024 + j] : b_hh[1024 + j];
    bias4[idx] = v;
  }
}

// Xb [T*B][160] bf16: row (t,b) = t==0 ? [obs[0],0] : [obs[t-1], action[t-1]]
__global__ void k_pack_x(const float* __restrict__ obs, const float* __restrict__ action,
                         u16* __restrict__ Xb) {
  const int n = TT * BB * 160;
  for (int idx = blockIdx.x * blockDim.x + threadIdx.x; idx < n;
       idx += gridDim.x * blockDim.x) {
    int rr = idx / 160, cc = idx - rr * 160;
    int t = rr / BB, b = rr - t * BB;
    float v;
    if (t == 0) v = (cc < OBS) ? obs[(size_t)b * OBS + cc] : 0.f;
    else        v = (cc < OBS) ? obs[((size_t)(t - 1) * BB + b) * OBS + cc]
                               : action[((size_t)(t - 1) * BB + b) * ACT + (cc - OBS)];
    Xb[idx] = f2bf(v);
  }
}

// ---------------- persistent GRU recurrence (v4': v3 partition + reg-weights) -----
// Grid (32 jt, 16 bt) = 512 blocks, 2/CU (launch_bounds(256,2) -> VGPR cap 256 so
// the compiler KEEPS the weight fragments resident; v4's (256,4) cap of 128 forced
// per-step rematerialization of the weight loads = regression).
// Each block: 16 batch rows x 16 j-cols. Gate weights in REGISTERS (wave w holds its
// gate's 16j x 512k tile as 16 bf16x8 frags/lane, loaded once): w0=r_h, w1=z_h,
// w2=n_h, w3 = all 3 x-gates (15 frags), x A-frag loaded per-lane from L2 Xb.
// All 16 MFMA A-rows real (no garbage). Cross-wave gate exchange via LDS.
// h crosses blocks via LLC only: A-h staging SC0|SC1 global_load_lds; h stores
// relaxed agent atomics (write-through). Group barrier (32 jt-blocks sharing bt):
// per-block flag (64B pad) + parallel 32-lane poll; __syncthreads() drains vmcnt so
// h is LLC-acked before the flag store. Flags monotone across chunk launches.
// LDS (u16 units): A-h@0 (16x512) ; exch@8192 = 6x256 f32. Total 22528 B.
__global__ __launch_bounds__(256, 2) void k_gru_seq(
    const u16* __restrict__ Wr, const u16* __restrict__ Wz,
    const u16* __restrict__ Wnh, const u16* __restrict__ Wni,
    const float* __restrict__ bias4, const u16* __restrict__ Xb,
    u16* __restrict__ hs,          // [TC][BB][512] bf16 (slot TC-1 carries across launches)
    float* __restrict__ h32c,      // [BB][512] fp32 carry
    const u16* __restrict__ zb,    // 1 KB zeros
    int* __restrict__ bars,        // flags, stride 16 ints (64 B)
    int t0, int TC)
{
  __shared__ __align__(16) u16 SB[11264];   // 22528 B
  const int jt = blockIdx.x, bt = blockIdx.y;
  const int tid = threadIdx.x, w = tid >> 6, lane = tid & 63;
  const int m16 = lane & 15, q = lane >> 4;

  // ---- load this wave's gate-weight fragments into registers (once) ----
  // frag wf[ks] = W[jt*16+m16][(ks*4+q)*8 ..]  (h-gates: ks 0..15)
  // wave3: wf[ks*3+g] over ks 0..4, g in {ni, r_x, z_x}
  bf16x8 wf[16];
#pragma unroll
  for (int i = 0; i < 16; ++i) wf[i] = (bf16x8){0, 0, 0, 0, 0, 0, 0, 0};
  {
    const int jr = jt * 16 + m16;
    if (w < 3) {
      const u16* Wg = (w == 0) ? Wr : (w == 1) ? Wz : Wnh;
      const int ws_ = (w == 2) ? 512 : 704;
#pragma unroll
      for (int ks = 0; ks < 16; ++ks)
        wf[ks] = *(const bf16x8*)&Wg[(size_t)jr * ws_ + (ks * 4 + q) * 8];
    } else {
#pragma unroll
      for (int ks = 0; ks < 5; ++ks) {
        int cb = ks * 4 + q;
        wf[ks * 3 + 0] = *(const bf16x8*)&Wni[(size_t)jr * 192 + cb * 8];
        wf[ks * 3 + 1] = *(const bf16x8*)&Wr[(size_t)jr * 704 + 512 + cb * 8];
        wf[ks * 3 + 2] = *(const bf16x8*)&Wz[(size_t)jr * 704 + 512 + cb * 8];
      }
    }
  }

  // ---- per-lane A-h stage descriptors: instr (w,n) stages row i = w*4+n (16 rows) ----
  u32 aoff[4];
#pragma unroll
  for (int n = 0; n < 4; ++n) {
    int i = w * 4 + n;
    aoff[n] = (u32)(bt * 16 + i) * 512 + (u32)(lane ^ (i & 7)) * 8;
  }

  // x-row for wave3 A-frag (all 16 rows real: bt*16+15 <= 255)
  const int xr = bt * 16 + m16;

  // ---- per-thread output ownership: (eb, ej) fixed forever; tid == eb*16+ej ----
  const int eb = tid >> 4;
  const int ej = tid & 15;
  const int gj = jt * 16 + ej;
  const int gbrow = bt * 16 + eb;
  const float br = bias4[gj], bz = bias4[512 + gj];
  const float bi = bias4[1024 + gj], bh = bias4[1536 + gj];
  float hv = 0.f;
  if (t0 > 0) hv = h32c[(size_t)gbrow * 512 + gj];

  u16* As = SB;
  float* exch = (float*)(SB + 8192);
  const int myflag = (bt * 32 + jt) * 16;
  const int pollflag = (bt * 32 + (lane & 31)) * 16;

  for (int s = 0; s < TC; ++s) {
    const int t = t0 + s;
    const int sp = (s == 0) ? TC - 1 : s - 1;
    const u16* hsrc = hs + (size_t)sp * BB * 512;
    const u16* xsrc = Xb + (size_t)t * BB * 160;
    const bool hzero = (t == 0);

    // stage A-h (16 rows, 16 instrs), device-coherent from LLC
#pragma unroll
    for (int n = 0; n < 4; ++n) {
      const u16* g = hzero ? zb : hsrc + aoff[n];
      __builtin_amdgcn_global_load_lds((const __attribute__((address_space(1))) u32*)g,
          (__attribute__((address_space(3))) u32*)(As + (w * 4 + n) * 512), 16, 0, AUX_SC);
    }
    __syncthreads();   // drains vmcnt before ds_read

    f32x4 acc0 = (f32x4){0.f, 0.f, 0.f, 0.f};
    f32x4 acc1 = (f32x4){0.f, 0.f, 0.f, 0.f};
    f32x4 acc2 = (f32x4){0.f, 0.f, 0.f, 0.f};
    if (w < 3) {
#pragma unroll
      for (int ks = 0; ks < 16; ++ks) {
        int cb = ks * 4 + q;
        bf16x8 af = *(const bf16x8*)&As[m16 * 512 + (cb ^ (m16 & 7)) * 8];
        acc0 = __builtin_amdgcn_mfma_f32_16x16x32_bf16(af, wf[ks], acc0, 0, 0, 0);
      }
    } else {
#pragma unroll
      for (int ks = 0; ks < 5; ++ks) {
        int cb = ks * 4 + q;
        bf16x8 af = *(const bf16x8*)&xsrc[(size_t)xr * 160 + cb * 8];
        acc0 = __builtin_amdgcn_mfma_f32_16x16x32_bf16(af, wf[ks * 3 + 0], acc0, 0, 0, 0);  // ni
        acc1 = __builtin_amdgcn_mfma_f32_16x16x32_bf16(af, wf[ks * 3 + 1], acc1, 0, 0, 0);  // r_x
        acc2 = __builtin_amdgcn_mfma_f32_16x16x32_bf16(af, wf[ks * 3 + 2], acc2, 0, 0, 0);  // z_x
      }
    }

    // gate tiles: 0=r_h 1=z_h 2=nh @ w*256 ; 3=ni@768 4=r_x@1024 5=z_x@1280
    // exch index = [C-row = batch row (16)][C-col = j (16)]
    if (w < 3) {
#pragma unroll
      for (int p = 0; p < 4; ++p)
        exch[w * 256 + (q * 4 + p) * 16 + m16] = acc0[p];
    } else {
#pragma unroll
      for (int p = 0; p < 4; ++p) {
        int o = (q * 4 + p) * 16 + m16;
        exch[768 + o]  = acc0[p];
        exch[1024 + o] = acc1[p];
        exch[1280 + o] = acc2[p];
      }
    }
    __syncthreads();   // exch visible; also fences As reads before next-step stage

    // combine + gates: thread owns (eb, ej)
    {
      float rs  = exch[tid]        + exch[1024 + tid];
      float zs  = exch[256 + tid]  + exch[1280 + tid];
      float nhv = exch[512 + tid];
      float niv = exch[768 + tid];
      float r = fast_sigmoid(rs + br);
      float z = fast_sigmoid(zs + bz);
      float n = fast_tanh(niv + bi + r * (nhv + bh));
      float h = (1.f - z) * n + z * hv;
      hv = h;
      float ho = __shfl_xor(h, 1);
      if ((ej & 1) == 0) {
        u32 pk = (u32)f2bf(h) | ((u32)f2bf(ho) << 16);
        __hip_atomic_store((u32*)&hs[((size_t)s * BB + gbrow) * 512 + gj], pk,
                           __ATOMIC_RELAXED, __HIP_MEMORY_SCOPE_AGENT);
      }
    }

    // flag barrier (32 jt-blocks sharing bt): sync drains vmcnt (h acked at LLC),
    // then one flag store + parallel 32-lane poll.
    __syncthreads();
    if (tid == 0)
      __hip_atomic_store(&bars[myflag], t + 1, __ATOMIC_RELAXED, __HIP_MEMORY_SCOPE_AGENT);
    if (w == 0) {
      int v = __hip_atomic_load(&bars[pollflag], __ATOMIC_RELAXED, __HIP_MEMORY_SCOPE_AGENT);
      while (__any(v < t + 1)) {
        __builtin_amdgcn_s_sleep(1);
        v = __hip_atomic_load(&bars[pollflag], __ATOMIC_RELAXED, __HIP_MEMORY_SCOPE_AGENT);
      }
    }
    __syncthreads();
  }

  h32c[(size_t)gbrow * 512 + gj] = hv;
}

// ---------------- MFMA GEMM (heads) ----------------
// C[N][M] = act( A[N][K] @ B[Mp][K]^T + bias[M] ); K mult of 64, N mult of 128.
__global__ __launch_bounds__(256) void k_mfma_gemm(
    const u16* __restrict__ A, const u16* __restrict__ B,
    const float* __restrict__ bias,
    float* __restrict__ outf, u16* __restrict__ outb,
    int N, int K, int M, int act)
{
  __shared__ u16 As[128 * 64];
  __shared__ u16 Bs[128 * 64];
  const int bn = blockIdx.y * 128;
  const int bm = blockIdx.x * 128;
  const int tid = threadIdx.x;
  const int w = tid >> 6, lane = tid & 63;
  const int wr = w >> 1, wc = w & 1;

  f32x4 acc[4][4];
#pragma unroll
  for (int i = 0; i < 4; ++i)
#pragma unroll
    for (int j = 0; j < 4; ++j) acc[i][j] = (f32x4){0.f, 0.f, 0.f, 0.f};

  const int lr8 = lane >> 3;
  const int lc8 = lane & 7;

  for (int kt = 0; kt < K; kt += 64) {
    __syncthreads();
#pragma unroll
    for (int i = 0; i < 4; ++i) {
      int r0 = (w * 4 + i) * 8;
      int r = r0 + lr8;
      int c = lc8 ^ (r & 7);
      const u16* ga = A + (size_t)(bn + r) * K + kt + c * 8;
      const u16* gb = B + (size_t)(bm + r) * K + kt + c * 8;
      __builtin_amdgcn_global_load_lds((const __attribute__((address_space(1))) u32*)ga,
                                       (__attribute__((address_space(3))) u32*)(As + r0 * 64), 16, 0, 0);
      __builtin_amdgcn_global_load_lds((const __attribute__((address_space(1))) u32*)gb,
                                       (__attribute__((address_space(3))) u32*)(Bs + r0 * 64), 16, 0, 0);
    }
    __syncthreads();

    const int m16 = lane & 15, q = lane >> 4;
#pragma unroll
    for (int kk = 0; kk < 2; ++kk) {
      bf16x8 af[4], bfr[4];
#pragma unroll
      for (int i = 0; i < 4; ++i) {
        int ra = wr * 64 + i * 16 + m16;
        af[i] = *(const bf16x8*)&As[ra * 64 + ((kk * 4 + q) ^ (ra & 7)) * 8];
        int rb = wc * 64 + i * 16 + m16;
        bfr[i] = *(const bf16x8*)&Bs[rb * 64 + ((kk * 4 + q) ^ (rb & 7)) * 8];
      }
#pragma unroll
      for (int i = 0; i < 4; ++i)
#pragma unroll
        for (int j = 0; j < 4; ++j)
          acc[i][j] = __builtin_amdgcn_mfma_f32_16x16x32_bf16(af[i], bfr[j], acc[i][j], 0, 0, 0);
    }
  }

  const int m16 = lane & 15, q = lane >> 4;
#pragma unroll
  for (int i = 0; i < 4; ++i) {
#pragma unroll
    for (int j = 0; j < 4; ++j) {
      int col = bm + wc * 64 + j * 16 + m16;
      if (col >= M) continue;
      float bs = bias[col];
#pragma unroll
      for (int p = 0; p < 4; ++p) {
        int row = bn + wr * 64 + i * 16 + q * 4 + p;
        float v = acc[i][j][p] + bs;
        if (act) v = (v > 0.f) ? v : (__expf(v) - 1.f);  // fast ELU (bf16-accurate)
        if (outf) outf[(size_t)row * M + col] = v;
        else      outb[(size_t)row * M + col] = f2bf(v);
      }
    }
  }
}

// ---------------- loss ----------------
__global__ __launch_bounds__(256) void k_loss(
    const float* __restrict__ obs, const float* __restrict__ action,
    const float* __restrict__ p_obs, const float* __restrict__ p_act,
    const float* __restrict__ p_rew, double* __restrict__ acc)
{
  const long long n1 = (long long)TT * BB * OBS;
  const long long n2 = (long long)TT * BB * ACT;
  const long long n  = n1 + n2 + n2;
  const float C = 0.91893853320467274178f;  // 0.5*ln(2*pi)
  double s = 0.0;
  for (long long idx = (long long)blockIdx.x * blockDim.x + threadIdx.x; idx < n;
       idx += (long long)gridDim.x * blockDim.x) {
    float d;
    if (idx < n1) {
      d = obs[idx] - p_obs[idx];
    } else if (idx < n1 + n2) {
      long long i = idx - n1;
      d = action[i] - p_act[i];
    } else {
      long long i = idx - n1 - n2;
      d = action[i] - p_rew[i >> 5];
    }
    s += (double)(0.5f * d * d + C);
  }
  __shared__ double red[256];
  red[threadIdx.x] = s;
  __syncthreads();
  for (int off = 128; off > 0; off >>= 1) {
    if ((int)threadIdx.x < off) red[threadIdx.x] += red[threadIdx.x + off];
    __syncthreads();
  }
  if (threadIdx.x == 0) atomicAdd(acc, red[0]);
}

__global__ void k_finalize(const double* __restrict__ acc, float* __restrict__ out) {
  if (threadIdx.x == 0) out[0] = (float)(acc[0] / (double)(TT * BB));
}

// ---------------- launch ----------------

extern "C" void kernel_launch(void* const* d_in, const int* in_sizes, int n_in,
                              void* d_out, int out_size, void* d_ws, size_t ws_size,
                              hipStream_t stream) {
  const float* obs    = (const float*)d_in[0];
  const float* action = (const float*)d_in[1];
  const float* w_ih = (const float*)d_in[3];
  const float* w_hh = (const float*)d_in[4];
  const float* b_ih = (const float*)d_in[5];
  const float* b_hh = (const float*)d_in[6];
  const float* hw[9] = {(const float*)d_in[7],  (const float*)d_in[9],  (const float*)d_in[11],
                        (const float*)d_in[13], (const float*)d_in[15], (const float*)d_in[17],
                        (const float*)d_in[19], (const float*)d_in[21], (const float*)d_in[23]};
  const float* hb[9] = {(const float*)d_in[8],  (const float*)d_in[10], (const float*)d_in[12],
                        (const float*)d_in[14], (const float*)d_in[16], (const float*)d_in[18],
                        (const float*)d_in[20], (const float*)d_in[22], (const float*)d_in[24]};
  const int hM[9]  = {512, 512, 128, 512, 512, 32, 512, 512, 1};
  const int hMp[9] = {512, 512, 128, 512, 512, 128, 512, 512, 128};

  float* out     = (float*)d_out;
  float* pre_obs = out + 1;
  float* pre_act = pre_obs + (size_t)TT * BB * OBS;
  float* pre_rew = pre_act + (size_t)TT * BB * ACT;

  // ---- workspace ----
  char* ws = (char*)d_ws;
  size_t off = 0;
  auto alloc = [&](size_t bytes) { void* p = ws + off; off = (off + bytes + 255) & ~(size_t)255; return p; };
  double* acc  = (double*)alloc(256);
  int* bars    = (int*)alloc(1024 * 64);          // padded flags
  u32* zerobuf = (u32*)alloc(1024);
  u16* Wr  = (u16*)alloc((size_t)512 * 704 * 2);
  u16* Wz  = (u16*)alloc((size_t)512 * 704 * 2);
  u16* Wnh = (u16*)alloc((size_t)512 * 512 * 2);
  u16* Wni = (u16*)alloc((size_t)512 * 192 * 2);
  float* bias4 = (float*)alloc(2048 * 4);
  u16* headb[9];
  for (int i = 0; i < 9; ++i) headb[i] = (u16*)alloc((size_t)hMp[i] * 512 * 2);
  float* h32c = (float*)alloc((size_t)BB * 512 * 4);
  u16* Xb     = (u16*)alloc((size_t)TT * BB * 160 * 2);   // 41.9 MB
  const size_t fixed = off;

  int TC = 512;
  while (TC > 8 && fixed + 3ull * TC * BB * 512 * 2ull + (1u << 20) > ws_size) TC >>= 1;
  u16* hs_chunk = (u16*)alloc((size_t)TC * BB * 512 * 2);
  u16* tmp1b    = (u16*)alloc((size_t)TC * BB * 512 * 2);
  u16* tmp2b    = (u16*)alloc((size_t)TC * BB * 512 * 2);
  const int CH = TC * BB;
  const int NCH = TT / TC;

  // ---- setup ----
  k_init<<<1, 256, 0, stream>>>(acc, bars, zerobuf);
  k_prep_w<<<512, 256, 0, stream>>>(w_ih, w_hh, b_ih, b_hh, Wr, Wz, Wnh, Wni, bias4);
  for (int i = 0; i < 9; ++i)
    k_convert_pad<<<512, 256, 0, stream>>>(hw[i], headb[i], hM[i], 512, hMp[i], 512);
  k_pack_x<<<4096, 256, 0, stream>>>(obs, action, Xb);

  for (int c = 0; c < NCH; ++c) {
    k_gru_seq<<<dim3(32, 16), 256, 0, stream>>>(
        Wr, Wz, Wnh, Wni, bias4, Xb, hs_chunk, h32c, (const u16*)zerobuf, bars, c * TC, TC);
    for (int h = 0; h < 3; ++h) {
      int M2 = hM[h * 3 + 2], Mp2 = hMp[h * 3 + 2];
      float* outp = (h == 0) ? pre_obs + (size_t)c * CH * OBS
                  : (h == 1) ? pre_act + (size_t)c * CH * ACT
                             : pre_rew + (size_t)c * CH;
      k_mfma_gemm<<<dim3(4, CH / 128), 256, 0, stream>>>(
          hs_chunk, headb[h * 3 + 0], hb[h * 3 + 0], nullptr, tmp1b, CH, 512, 512, 1);
      k_mfma_gemm<<<dim3(4, CH / 128), 256, 0, stream>>>(
          tmp1b, headb[h * 3 + 1], hb[h * 3 + 1], nullptr, tmp2b, CH, 512, 512, 1);
      k_mfma_gemm<<<dim3(Mp2 / 128, CH / 128), 256, 0, stream>>>(
          tmp2b, headb[h * 3 + 2], hb[h * 3 + 2], outp, nullptr, CH, 512, M2, 0);
    }
  }

  k_loss<<<2048, 256, 0, stream>>>(obs, action, pre_obs, pre_act, pre_rew, acc);
  k_finalize<<<1, 64, 0, stream>>>(acc, out);
}

// Round 10
// 2915.793 us; speedup vs baseline: 1.1209x; 1.0063x over previous
//
#include <hip/hip_runtime.h>
#include <math.h>

#define TT 512
#define BB 256
#define OBS 128
#define ACT 32
#define HID 512
#define AUX_SC 0x11  // SC0|SC1 cache policy: device-scope coherent (bypass L1/L2, read LLC)

typedef unsigned short u16;
typedef unsigned int u32;
typedef __attribute__((ext_vector_type(8))) short bf16x8;  // 8 bf16 = 4 VGPRs
typedef __attribute__((ext_vector_type(4))) float f32x4;

__device__ __forceinline__ u16 f2bf(float v) {
  u32 u = __float_as_uint(v);
  u = (u + 0x7fff + ((u >> 16) & 1)) >> 16;  // RNE
  return (u16)u;
}

// fast transcendentals (v_exp_f32-based) — bf16-accurate, saturate-safe
__device__ __forceinline__ float fast_sigmoid(float x) {
  return 1.f / (1.f + __expf(-x));
}
__device__ __forceinline__ float fast_tanh(float x) {
  float e = __expf(-2.f * fabsf(x));   // e in (0,1], no overflow
  float t = (1.f - e) / (1.f + e);
  return copysignf(t, x);
}

// ---------------- init / setup kernels ----------------

__global__ void k_init(double* acc, int* bars, u32* zb) {
  int tid = threadIdx.x;
  if (tid == 0) acc[0] = 0.0;
  for (int i = tid; i < 1024; i += 256) bars[i] = 0;  // group-contiguous flags
  zb[tid] = 0;                        // 256 u32 = 1 KB zero buffer
}

// dst bf16 [Mp][Kp] = zero-padded convert of src fp32 [M][K]   (head weights)
__global__ void k_convert_pad(const float* __restrict__ src, u16* __restrict__ dst,
                              int M, int K, int Mp, int Kp) {
  const int n = Mp * Kp;
  for (int idx = blockIdx.x * blockDim.x + threadIdx.x; idx < n;
       idx += gridDim.x * blockDim.x) {
    int m = idx / Kp, k = idx - m * Kp;
    float v = (m < M && k < K) ? src[(size_t)m * K + k] : 0.f;
    dst[idx] = f2bf(v);
  }
}

// Build recurrence weight arrays:
// Wr/Wz [512][704]: [whh_gate | wih_gate | 0pad32]; Wnh [512][512]; Wni [512][192];
// bias4 [4][512]: r: bih+bhh, z: bih+bhh, n_i: bih, n_h: bhh
__global__ void k_prep_w(const float* __restrict__ w_ih, const float* __restrict__ w_hh,
                         const float* __restrict__ b_ih, const float* __restrict__ b_hh,
                         u16* __restrict__ Wr, u16* __restrict__ Wz,
                         u16* __restrict__ Wnh, u16* __restrict__ Wni,
                         float* __restrict__ bias4) {
  const int stride = gridDim.x * blockDim.x;
  const int t0 = blockIdx.x * blockDim.x + threadIdx.x;
  for (int idx = t0; idx < 512 * 704; idx += stride) {
    int j = idx / 704, k = idx - j * 704;
    float vr, vz;
    if (k < 512)      { vr = w_hh[(size_t)j * 512 + k];        vz = w_hh[(size_t)(512 + j) * 512 + k]; }
    else if (k < 672) { vr = w_ih[(size_t)j * 160 + (k - 512)]; vz = w_ih[(size_t)(512 + j) * 160 + (k - 512)]; }
    else              { vr = 0.f; vz = 0.f; }
    Wr[idx] = f2bf(vr); Wz[idx] = f2bf(vz);
  }
  for (int idx = t0; idx < 512 * 512; idx += stride) {
    int j = idx >> 9, k = idx & 511;
    Wnh[idx] = f2bf(w_hh[(size_t)(1024 + j) * 512 + k]);
  }
  for (int idx = t0; idx < 512 * 192; idx += stride) {
    int j = idx / 192, k = idx - j * 192;
    Wni[idx] = f2bf(k < 160 ? w_ih[(size_t)(1024 + j) * 160 + k] : 0.f);
  }
  for (int idx = t0; idx < 2048; idx += stride) {
    int g = idx >> 9, j = idx & 511;
    float v = (g == 0) ? b_ih[j] + b_hh[j]
            : (g == 1) ? b_ih[512 + j] + b_hh[512 + j]
            : (g == 2) ? b_ih[1024 + j] : b_hh[1024 + j];
    bias4[idx] = v;
  }
}

// Xb [T*B][160] bf16: row (t,b) = t==0 ? [obs[0],0] : [obs[t-1], action[t-1]]
__global__ void k_pack_x(const float* __restrict__ obs, const float* __restrict__ action,
                         u16* __restrict__ Xb) {
  const int n = TT * BB * 160;
  for (int idx = blockIdx.x * blockDim.x + threadIdx.x; idx < n;
       idx += gridDim.x * blockDim.x) {
    int rr = idx / 160, cc = idx - rr * 160;
    int t = rr / BB, b = rr - t * BB;
    float v;
    if (t == 0) v = (cc < OBS) ? obs[(size_t)b * OBS + cc] : 0.f;
    else        v = (cc < OBS) ? obs[((size_t)(t - 1) * BB + b) * OBS + cc]
                               : action[((size_t)(t - 1) * BB + b) * ACT + (cc - OBS)];
    Xb[idx] = f2bf(v);
  }
}

// ---------------- persistent GRU recurrence (v5: forced reg-weights, packed flags) --
// Grid (32 jt, 16 bt) = 512 blocks. Each block: 16 batch rows x 16 j-cols.
// Gate weights in REGISTERS: wave w holds its gate's 16j x 512k tile as 16 bf16x8
// frags/lane, loaded ONCE; an opaque-def inline asm ("+v") after the load prevents
// the compiler from rematerializing the loads inside the step loop (v4/v4' failure:
// VGPR_Count=64/68 proved remat; FETCH_SIZE showed ~34 MB/step of weight re-reads).
// w0=r_h, w1=z_h, w2=n_h, w3 = all 3 x-gates; x A-frag loaded per-lane from L2 Xb.
// Cross-wave gate exchange via LDS. h crosses blocks via LLC only: A-h staging
// SC0|SC1 global_load_lds; h stores relaxed agent atomics (write-through).
// Group barrier (32 jt-blocks sharing bt): per-block flag, GROUP-CONTIGUOUS
// (bars[bt*64+jt], 4 B stride -> one 32-lane poll touches 2 cachelines instead of
// 32). __syncthreads() drains vmcnt so h is LLC-acked before the flag store; pollers
// use agent-scope loads. Flags monotone across chunk launches.
// LDS (u16 units): A-h@0 (16x512) ; exch@8192 = 6x256 f32. Total 22528 B.
__global__ __launch_bounds__(256, 2) void k_gru_seq(
    const u16* __restrict__ Wr, const u16* __restrict__ Wz,
    const u16* __restrict__ Wnh, const u16* __restrict__ Wni,
    const float* __restrict__ bias4, const u16* __restrict__ Xb,
    u16* __restrict__ hs,          // [TC][BB][512] bf16 (slot TC-1 carries across launches)
    float* __restrict__ h32c,      // [BB][512] fp32 carry
    const u16* __restrict__ zb,    // 1 KB zeros
    int* __restrict__ bars,        // flags: bars[bt*64 + jt], groups 256 B apart
    int t0, int TC)
{
  __shared__ __align__(16) u16 SB[11264];   // 22528 B
  const int jt = blockIdx.x, bt = blockIdx.y;
  const int tid = threadIdx.x, w = tid >> 6, lane = tid & 63;
  const int m16 = lane & 15, q = lane >> 4;

  // ---- load this wave's gate-weight fragments into registers (once) ----
  // frag wf[ks] = W[jt*16+m16][(ks*4+q)*8 ..]  (h-gates: ks 0..15)
  // wave3: wf[ks*3+g] over ks 0..4, g in {ni, r_x, z_x}
  bf16x8 wf[16];
#pragma unroll
  for (int i = 0; i < 16; ++i) wf[i] = (bf16x8){0, 0, 0, 0, 0, 0, 0, 0};
  {
    const int jr = jt * 16 + m16;
    if (w < 3) {
      const u16* Wg = (w == 0) ? Wr : (w == 1) ? Wz : Wnh;
      const int ws_ = (w == 2) ? 512 : 704;
#pragma unroll
      for (int ks = 0; ks < 16; ++ks)
        wf[ks] = *(const bf16x8*)&Wg[(size_t)jr * ws_ + (ks * 4 + q) * 8];
    } else {
#pragma unroll
      for (int ks = 0; ks < 5; ++ks) {
        int cb = ks * 4 + q;
        wf[ks * 3 + 0] = *(const bf16x8*)&Wni[(size_t)jr * 192 + cb * 8];
        wf[ks * 3 + 1] = *(const bf16x8*)&Wr[(size_t)jr * 704 + 512 + cb * 8];
        wf[ks * 3 + 2] = *(const bf16x8*)&Wz[(size_t)jr * 704 + 512 + cb * 8];
      }
    }
  }
  // opaque def: compiler cannot rematerialize the loads past this point; the
  // fragments must stay resident in VGPRs across the step loop.
#pragma unroll
  for (int i = 0; i < 16; ++i) asm volatile("" : "+v"(wf[i]));

  // ---- per-lane A-h stage descriptors: instr (w,n) stages row i = w*4+n (16 rows) ----
  u32 aoff[4];
#pragma unroll
  for (int n = 0; n < 4; ++n) {
    int i = w * 4 + n;
    aoff[n] = (u32)(bt * 16 + i) * 512 + (u32)(lane ^ (i & 7)) * 8;
  }

  // x-row for wave3 A-frag (all 16 rows real)
  const int xr = bt * 16 + m16;

  // ---- per-thread output ownership: (eb, ej) fixed forever; tid == eb*16+ej ----
  const int eb = tid >> 4;
  const int ej = tid & 15;
  const int gj = jt * 16 + ej;
  const int gbrow = bt * 16 + eb;
  const float br = bias4[gj], bz = bias4[512 + gj];
  const float bi = bias4[1024 + gj], bh = bias4[1536 + gj];
  float hv = 0.f;
  if (t0 > 0) hv = h32c[(size_t)gbrow * 512 + gj];

  u16* As = SB;
  float* exch = (float*)(SB + 8192);
  const int myflag = bt * 64 + jt;
  const int pollflag = bt * 64 + (lane & 31);

  for (int s = 0; s < TC; ++s) {
    const int t = t0 + s;
    const int sp = (s == 0) ? TC - 1 : s - 1;
    const u16* hsrc = hs + (size_t)sp * BB * 512;
    const u16* xsrc = Xb + (size_t)t * BB * 160;
    const bool hzero = (t == 0);

    // stage A-h (16 rows, 16 instrs), device-coherent from LLC
#pragma unroll
    for (int n = 0; n < 4; ++n) {
      const u16* g = hzero ? zb : hsrc + aoff[n];
      __builtin_amdgcn_global_load_lds((const __attribute__((address_space(1))) u32*)g,
          (__attribute__((address_space(3))) u32*)(As + (w * 4 + n) * 512), 16, 0, AUX_SC);
    }
    __syncthreads();   // drains vmcnt before ds_read

    f32x4 acc0 = (f32x4){0.f, 0.f, 0.f, 0.f};
    f32x4 acc1 = (f32x4){0.f, 0.f, 0.f, 0.f};
    f32x4 acc2 = (f32x4){0.f, 0.f, 0.f, 0.f};
    if (w < 3) {
#pragma unroll
      for (int ks = 0; ks < 16; ++ks) {
        int cb = ks * 4 + q;
        bf16x8 af = *(const bf16x8*)&As[m16 * 512 + (cb ^ (m16 & 7)) * 8];
        acc0 = __builtin_amdgcn_mfma_f32_16x16x32_bf16(af, wf[ks], acc0, 0, 0, 0);
      }
    } else {
#pragma unroll
      for (int ks = 0; ks < 5; ++ks) {
        int cb = ks * 4 + q;
        bf16x8 af = *(const bf16x8*)&xsrc[(size_t)xr * 160 + cb * 8];
        acc0 = __builtin_amdgcn_mfma_f32_16x16x32_bf16(af, wf[ks * 3 + 0], acc0, 0, 0, 0);  // ni
        acc1 = __builtin_amdgcn_mfma_f32_16x16x32_bf16(af, wf[ks * 3 + 1], acc1, 0, 0, 0);  // r_x
        acc2 = __builtin_amdgcn_mfma_f32_16x16x32_bf16(af, wf[ks * 3 + 2], acc2, 0, 0, 0);  // z_x
      }
    }

    // gate tiles: 0=r_h 1=z_h 2=nh @ w*256 ; 3=ni@768 4=r_x@1024 5=z_x@1280
    // exch index = [C-row = batch row (16)][C-col = j (16)]
    if (w < 3) {
#pragma unroll
      for (int p = 0; p < 4; ++p)
        exch[w * 256 + (q * 4 + p) * 16 + m16] = acc0[p];
    } else {
#pragma unroll
      for (int p = 0; p < 4; ++p) {
        int o = (q * 4 + p) * 16 + m16;
        exch[768 + o]  = acc0[p];
        exch[1024 + o] = acc1[p];
        exch[1280 + o] = acc2[p];
      }
    }
    __syncthreads();   // exch visible; also fences As reads before next-step stage

    // combine + gates: thread owns (eb, ej)
    {
      float rs  = exch[tid]        + exch[1024 + tid];
      float zs  = exch[256 + tid]  + exch[1280 + tid];
      float nhv = exch[512 + tid];
      float niv = exch[768 + tid];
      float r = fast_sigmoid(rs + br);
      float z = fast_sigmoid(zs + bz);
      float n = fast_tanh(niv + bi + r * (nhv + bh));
      float h = (1.f - z) * n + z * hv;
      hv = h;
      float ho = __shfl_xor(h, 1);
      if ((ej & 1) == 0) {
        u32 pk = (u32)f2bf(h) | ((u32)f2bf(ho) << 16);
        __hip_atomic_store((u32*)&hs[((size_t)s * BB + gbrow) * 512 + gj], pk,
                           __ATOMIC_RELAXED, __HIP_MEMORY_SCOPE_AGENT);
      }
    }

    // flag barrier (32 jt-blocks sharing bt): sync drains vmcnt (h acked at LLC),
    // then one flag store + parallel 32-lane poll over a 128 B flag window.
    __syncthreads();
    if (tid == 0)
      __hip_atomic_store(&bars[myflag], t + 1, __ATOMIC_RELAXED, __HIP_MEMORY_SCOPE_AGENT);
    if (w == 0) {
      int v = __hip_atomic_load(&bars[pollflag], __ATOMIC_RELAXED, __HIP_MEMORY_SCOPE_AGENT);
      while (__any(v < t + 1)) {
        __builtin_amdgcn_s_sleep(1);
        v = __hip_atomic_load(&bars[pollflag], __ATOMIC_RELAXED, __HIP_MEMORY_SCOPE_AGENT);
      }
    }
    __syncthreads();
  }

  h32c[(size_t)gbrow * 512 + gj] = hv;
}

// ---------------- MFMA GEMM (heads) ----------------
// C[N][M] = act( A[N][K] @ B[Mp][K]^T + bias[M] ); K mult of 64, N mult of 128.
__global__ __launch_bounds__(256) void k_mfma_gemm(
    const u16* __restrict__ A, const u16* __restrict__ B,
    const float* __restrict__ bias,
    float* __restrict__ outf, u16* __restrict__ outb,
    int N, int K, int M, int act)
{
  __shared__ u16 As[128 * 64];
  __shared__ u16 Bs[128 * 64];
  const int bn = blockIdx.y * 128;
  const int bm = blockIdx.x * 128;
  const int tid = threadIdx.x;
  const int w = tid >> 6, lane = tid & 63;
  const int wr = w >> 1, wc = w & 1;

  f32x4 acc[4][4];
#pragma unroll
  for (int i = 0; i < 4; ++i)
#pragma unroll
    for (int j = 0; j < 4; ++j) acc[i][j] = (f32x4){0.f, 0.f, 0.f, 0.f};

  const int lr8 = lane >> 3;
  const int lc8 = lane & 7;

  for (int kt = 0; kt < K; kt += 64) {
    __syncthreads();
#pragma unroll
    for (int i = 0; i < 4; ++i) {
      int r0 = (w * 4 + i) * 8;
      int r = r0 + lr8;
      int c = lc8 ^ (r & 7);
      const u16* ga = A + (size_t)(bn + r) * K + kt + c * 8;
      const u16* gb = B + (size_t)(bm + r) * K + kt + c * 8;
      __builtin_amdgcn_global_load_lds((const __attribute__((address_space(1))) u32*)ga,
                                       (__attribute__((address_space(3))) u32*)(As + r0 * 64), 16, 0, 0);
      __builtin_amdgcn_global_load_lds((const __attribute__((address_space(1))) u32*)gb,
                                       (__attribute__((address_space(3))) u32*)(Bs + r0 * 64), 16, 0, 0);
    }
    __syncthreads();

    const int m16 = lane & 15, q = lane >> 4;
#pragma unroll
    for (int kk = 0; kk < 2; ++kk) {
      bf16x8 af[4], bfr[4];
#pragma unroll
      for (int i = 0; i < 4; ++i) {
        int ra = wr * 64 + i * 16 + m16;
        af[i] = *(const bf16x8*)&As[ra * 64 + ((kk * 4 + q) ^ (ra & 7)) * 8];
        int rb = wc * 64 + i * 16 + m16;
        bfr[i] = *(const bf16x8*)&Bs[rb * 64 + ((kk * 4 + q) ^ (rb & 7)) * 8];
      }
#pragma unroll
      for (int i = 0; i < 4; ++i)
#pragma unroll
        for (int j = 0; j < 4; ++j)
          acc[i][j] = __builtin_amdgcn_mfma_f32_16x16x32_bf16(af[i], bfr[j], acc[i][j], 0, 0, 0);
    }
  }

  const int m16 = lane & 15, q = lane >> 4;
#pragma unroll
  for (int i = 0; i < 4; ++i) {
#pragma unroll
    for (int j = 0; j < 4; ++j) {
      int col = bm + wc * 64 + j * 16 + m16;
      if (col >= M) continue;
      float bs = bias[col];
#pragma unroll
      for (int p = 0; p < 4; ++p) {
        int row = bn + wr * 64 + i * 16 + q * 4 + p;
        float v = acc[i][j][p] + bs;
        if (act) v = (v > 0.f) ? v : (__expf(v) - 1.f);  // fast ELU (bf16-accurate)
        if (outf) outf[(size_t)row * M + col] = v;
        else      outb[(size_t)row * M + col] = f2bf(v);
      }
    }
  }
}

// ---------------- loss ----------------
__global__ __launch_bounds__(256) void k_loss(
    const float* __restrict__ obs, const float* __restrict__ action,
    const float* __restrict__ p_obs, const float* __restrict__ p_act,
    const float* __restrict__ p_rew, double* __restrict__ acc)
{
  const long long n1 = (long long)TT * BB * OBS;
  const long long n2 = (long long)TT * BB * ACT;
  const long long n  = n1 + n2 + n2;
  const float C = 0.91893853320467274178f;  // 0.5*ln(2*pi)
  double s = 0.0;
  for (long long idx = (long long)blockIdx.x * blockDim.x + threadIdx.x; idx < n;
       idx += (long long)gridDim.x * blockDim.x) {
    float d;
    if (idx < n1) {
      d = obs[idx] - p_obs[idx];
    } else if (idx < n1 + n2) {
      long long i = idx - n1;
      d = action[i] - p_act[i];
    } else {
      long long i = idx - n1 - n2;
      d = action[i] - p_rew[i >> 5];
    }
    s += (double)(0.5f * d * d + C);
  }
  __shared__ double red[256];
  red[threadIdx.x] = s;
  __syncthreads();
  for (int off = 128; off > 0; off >>= 1) {
    if ((int)threadIdx.x < off) red[threadIdx.x] += red[threadIdx.x + off];
    __syncthreads();
  }
  if (threadIdx.x == 0) atomicAdd(acc, red[0]);
}

__global__ void k_finalize(const double* __restrict__ acc, float* __restrict__ out) {
  if (threadIdx.x == 0) out[0] = (float)(acc[0] / (double)(TT * BB));
}

// ---------------- launch ----------------

extern "C" void kernel_launch(void* const* d_in, const int* in_sizes, int n_in,
                              void* d_out, int out_size, void* d_ws, size_t ws_size,
                              hipStream_t stream) {
  const float* obs    = (const float*)d_in[0];
  const float* action = (const float*)d_in[1];
  const float* w_ih = (const float*)d_in[3];
  const float* w_hh = (const float*)d_in[4];
  const float* b_ih = (const float*)d_in[5];
  const float* b_hh = (const float*)d_in[6];
  const float* hw[9] = {(const float*)d_in[7],  (const float*)d_in[9],  (const float*)d_in[11],
                        (const float*)d_in[13], (const float*)d_in[15], (const float*)d_in[17],
                        (const float*)d_in[19], (const float*)d_in[21], (const float*)d_in[23]};
  const float* hb[9] = {(const float*)d_in[8],  (const float*)d_in[10], (const float*)d_in[12],
                        (const float*)d_in[14], (const float*)d_in[16], (const float*)d_in[18],
                        (const float*)d_in[20], (const float*)d_in[22], (const float*)d_in[24]};
  const int hM[9]  = {512, 512, 128, 512, 512, 32, 512, 512, 1};
  const int hMp[9] = {512, 512, 128, 512, 512, 128, 512, 512, 128};

  float* out     = (float*)d_out;
  float* pre_obs = out + 1;
  float* pre_act = pre_obs + (size_t)TT * BB * OBS;
  float* pre_rew = pre_act + (size_t)TT * BB * ACT;

  // ---- workspace ----
  char* ws = (char*)d_ws;
  size_t off = 0;
  auto alloc = [&](size_t bytes) { void* p = ws + off; off = (off + bytes + 255) & ~(size_t)255; return p; };
  double* acc  = (double*)alloc(256);
  int* bars    = (int*)alloc(1024 * 64);          // flags (first 1024 ints used)
  u32* zerobuf = (u32*)alloc(1024);
  u16* Wr  = (u16*)alloc((size_t)512 * 704 * 2);
  u16* Wz  = (u16*)alloc((size_t)512 * 704 * 2);
  u16* Wnh = (u16*)alloc((size_t)512 * 512 * 2);
  u16* Wni = (u16*)alloc((size_t)512 * 192 * 2);
  float* bias4 = (float*)alloc(2048 * 4);
  u16* headb[9];
  for (int i = 0; i < 9; ++i) headb[i] = (u16*)alloc((size_t)hMp[i] * 512 * 2);
  float* h32c = (float*)alloc((size_t)BB * 512 * 4);
  u16* Xb     = (u16*)alloc((size_t)TT * BB * 160 * 2);   // 41.9 MB
  const size_t fixed = off;

  int TC = 512;
  while (TC > 8 && fixed + 3ull * TC * BB * 512 * 2ull + (1u << 20) > ws_size) TC >>= 1;
  u16* hs_chunk = (u16*)alloc((size_t)TC * BB * 512 * 2);
  u16* tmp1b    = (u16*)alloc((size_t)TC * BB * 512 * 2);
  u16* tmp2b    = (u16*)alloc((size_t)TC * BB * 512 * 2);
  const int CH = TC * BB;
  const int NCH = TT / TC;

  // ---- setup ----
  k_init<<<1, 256, 0, stream>>>(acc, bars, zerobuf);
  k_prep_w<<<512, 256, 0, stream>>>(w_ih, w_hh, b_ih, b_hh, Wr, Wz, Wnh, Wni, bias4);
  for (int i = 0; i < 9; ++i)
    k_convert_pad<<<512, 256, 0, stream>>>(hw[i], headb[i], hM[i], 512, hMp[i], 512);
  k_pack_x<<<4096, 256, 0, stream>>>(obs, action, Xb);

  for (int c = 0; c < NCH; ++c) {
    k_gru_seq<<<dim3(32, 16), 256, 0, stream>>>(
        Wr, Wz, Wnh, Wni, bias4, Xb, hs_chunk, h32c, (const u16*)zerobuf, bars, c * TC, TC);
    for (int h = 0; h < 3; ++h) {
      int M2 = hM[h * 3 + 2], Mp2 = hMp[h * 3 + 2];
      float* outp = (h == 0) ? pre_obs + (size_t)c * CH * OBS
                  : (h == 1) ? pre_act + (size_t)c * CH * ACT
                             : pre_rew + (size_t)c * CH;
      k_mfma_gemm<<<dim3(4, CH / 128), 256, 0, stream>>>(
          hs_chunk, headb[h * 3 + 0], hb[h * 3 + 0], nullptr, tmp1b, CH, 512, 512, 1);
      k_mfma_gemm<<<dim3(4, CH / 128), 256, 0, stream>>>(
          tmp1b, headb[h * 3 + 1], hb[h * 3 + 1], nullptr, tmp2b, CH, 512, 512, 1);
      k_mfma_gemm<<<dim3(Mp2 / 128, CH / 128), 256, 0, stream>>>(
          tmp2b, headb[h * 3 + 2], hb[h * 3 + 2], outp, nullptr, CH, 512, M2, 0);
    }
  }

  k_loss<<<2048, 256, 0, stream>>>(obs, action, pre_obs, pre_act, pre_rew, acc);
  k_finalize<<<1, 64, 0, stream>>>(acc, out);
}